// Round 1
// baseline (370.261 us; speedup 1.0000x reference)
//
#include <hip/hip_runtime.h>
#include <math.h>

// Problem constants (hardcoded in reference source)
#define BATCH 128
#define KS    512
#define BK    (BATCH * KS)

// ws layout (floats):
//   [0,    BK)  sum0 = column sums of exp(logQ0)  -> q1 = log(sum0) - logK
//   [BK,  2BK)  sum1 = column sums of exp(logQ1)  -> q0 = log(sum1) - logK
//   [2BK, 3BK)  S    = sum_k ea[b,k] * exp(logP1[b,k,j])
//   [3BK, 4BK)  ea   = exp(logP0 - q0) = KS * exp(logP0) / sum1

// --- K1: column sums of exp() over both Q tensors, row-split for parallelism ---
// grid: (RSPLIT, BATCH, 2), block: 128 threads, each thread owns 4 consecutive cols.
#define RSPLIT 8
#define ROWS_PER_CHUNK (KS / RSPLIT)   // 64

__global__ __launch_bounds__(128) void colsum_exp_kernel(const float* __restrict__ Q0,
                                                         const float* __restrict__ Q1,
                                                         float* __restrict__ ws) {
    const int rchunk = blockIdx.x;           // 0..RSPLIT-1
    const int b      = blockIdx.y;           // 0..BATCH-1
    const int t      = blockIdx.z;           // 0 -> Q0/sum0, 1 -> Q1/sum1
    const float* __restrict__ Q = t ? Q1 : Q0;
    float* __restrict__ dst = ws + (size_t)t * BK;

    const int j = threadIdx.x * 4;           // column base (0..508)
    const float4* __restrict__ src = reinterpret_cast<const float4*>(
        Q + (size_t)b * KS * KS + (size_t)rchunk * ROWS_PER_CHUNK * KS + j);

    float a0 = 0.f, a1 = 0.f, a2 = 0.f, a3 = 0.f;
    #pragma unroll 4
    for (int r = 0; r < ROWS_PER_CHUNK; ++r) {
        float4 v = src[(size_t)r * (KS / 4)];
        a0 += __expf(v.x);
        a1 += __expf(v.y);
        a2 += __expf(v.z);
        a3 += __expf(v.w);
    }
    atomicAdd(&dst[b * KS + j + 0], a0);
    atomicAdd(&dst[b * KS + j + 1], a1);
    atomicAdd(&dst[b * KS + j + 2], a2);
    atomicAdd(&dst[b * KS + j + 3], a3);
}

// --- K2: ea[b,j] = KS * exp(logP0[b,j]) / sum1[b,j] ---
__global__ __launch_bounds__(256) void ea_kernel(const float* __restrict__ P0,
                                                 float* __restrict__ ws) {
    int i = blockIdx.x * blockDim.x + threadIdx.x;   // 0..BK-1
    float s1 = ws[BK + i];
    ws[3 * BK + i] = (float)KS * __expf(P0[i]) / s1;
}

// --- K3: S[b,j] = sum_k ea[b,k] * exp(logP1[b,k,j]), row-split ---
__global__ __launch_bounds__(128) void wsum_kernel(const float* __restrict__ P1,
                                                   float* __restrict__ ws) {
    const int rchunk = blockIdx.x;
    const int b      = blockIdx.y;
    const float* __restrict__ ea = ws + 3 * BK + (size_t)b * KS;
    float* __restrict__ S = ws + 2 * BK;

    const int j  = threadIdx.x * 4;
    const int r0 = rchunk * ROWS_PER_CHUNK;
    const float4* __restrict__ src = reinterpret_cast<const float4*>(
        P1 + (size_t)b * KS * KS + (size_t)r0 * KS + j);

    float a0 = 0.f, a1 = 0.f, a2 = 0.f, a3 = 0.f;
    #pragma unroll 4
    for (int r = 0; r < ROWS_PER_CHUNK; ++r) {
        float w  = ea[r0 + r];               // wave-uniform broadcast load
        float4 v = src[(size_t)r * (KS / 4)];
        a0 += w * __expf(v.x);
        a1 += w * __expf(v.y);
        a2 += w * __expf(v.z);
        a3 += w * __expf(v.w);
    }
    atomicAdd(&S[b * KS + j + 0], a0);
    atomicAdd(&S[b * KS + j + 1], a1);
    atomicAdd(&S[b * KS + j + 2], a2);
    atomicAdd(&S[b * KS + j + 3], a3);
}

// --- K4: per-batch r_b = log( sum_j S[b,j]*exp(logP2[b,j])/sum0[b,j] ) - logK;
//         out[0] -= r_b  (accumulated via atomicAdd) ---
__global__ __launch_bounds__(128) void finish_kernel(const float* __restrict__ P2,
                                                     const float* __restrict__ ws,
                                                     float* __restrict__ out) {
    const int b = blockIdx.x;
    const float* __restrict__ S    = ws + 2 * BK + (size_t)b * KS;
    const float* __restrict__ sum0 = ws + (size_t)b * KS;

    const int j = threadIdx.x * 4;
    float t = 0.f;
    #pragma unroll
    for (int c = 0; c < 4; ++c) {
        int jj = j + c;
        t += S[jj] * __expf(P2[(size_t)b * KS + jj]) / sum0[jj];
    }
    // wave (64-lane) reduce, then cross-wave combine (2 waves)
    #pragma unroll
    for (int off = 32; off > 0; off >>= 1) t += __shfl_down(t, off);

    __shared__ float partial[2];
    if ((threadIdx.x & 63) == 0) partial[threadIdx.x >> 6] = t;
    __syncthreads();
    if (threadIdx.x == 0) {
        float tot = partial[0] + partial[1];
        float r = logf(tot) - logf((float)KS);
        atomicAdd(out, -r);
    }
}

extern "C" void kernel_launch(void* const* d_in, const int* in_sizes, int n_in,
                              void* d_out, int out_size, void* d_ws, size_t ws_size,
                              hipStream_t stream) {
    const float* Q0 = (const float*)d_in[0];   // logQ0 [B,K,K]
    const float* Q1 = (const float*)d_in[1];   // logQ1 [B,K,K]
    const float* P0 = (const float*)d_in[2];   // logP0 [B,1,K]
    const float* P1 = (const float*)d_in[3];   // logP1 [B,K,K]
    const float* P2 = (const float*)d_in[4];   // logP2 [B,K,1]
    float* out = (float*)d_out;
    float* ws  = (float*)d_ws;

    // zero accumulators (ws is re-poisoned to 0xAA before every launch)
    hipMemsetAsync(d_out, 0, sizeof(float), stream);
    hipMemsetAsync(d_ws, 0, (size_t)3 * BK * sizeof(float), stream);

    colsum_exp_kernel<<<dim3(RSPLIT, BATCH, 2), 128, 0, stream>>>(Q0, Q1, ws);
    ea_kernel<<<BK / 256, 256, 0, stream>>>(P0, ws);
    wsum_kernel<<<dim3(RSPLIT, BATCH), 128, 0, stream>>>(P1, ws);
    finish_kernel<<<BATCH, 128, 0, stream>>>(P2, ws, out);
}